// Round 1
// baseline (526.659 us; speedup 1.0000x reference)
//
#include <hip/hip_runtime.h>

#define NBINS  16
#define TPB    256
#define BLOCKS 1024        // 4 blocks/CU co-resident (35KB LDS x 4 = 140KB < 160KB)
#define DUMMY  16          // dead-slot redirect row (17th plane row, never read)

// d_ws layout: partial[cell * BLOCKS + blockIdx]; cells 0..15 cnt, 16..31 sum,
// 32..47 sumsq, 48 = sum (wq-w)^2.  49*1024 floats ~= 200 KB.
//
// vs previous version (160us main kernel, latency-bound: 15% VALU / 21% HBM / 31% occ):
//  - per-iter dedup of the 4 bin ids in registers -> the 4 surviving sv_pl RMWs
//    have provably distinct addresses, so reads are batched behind ONE lgkmcnt
//    wait instead of 8 serialized read-wait-add-write chains (dead slots write
//    to a dummy 17th row; HW in-order DS handles cross-iteration aliasing).
//  - per-bin counts moved from LDS to 16x8-bit fields packed in two u64 VGPRs
//    (flushed every 32 iters; exact integer arithmetic) -> halves DS instrs and
//    frees 16KB LDS -> 4 blocks/CU instead of 3.
//  - 1-deep register prefetch of next float4 pair to cover HBM latency.

__global__ __launch_bounds__(TPB, 4) void binreg_main(
    const float* __restrict__ w, const float* __restrict__ wq,
    const float* __restrict__ alpha_p, const int* __restrict__ nbit_p,
    float* __restrict__ partial, long long n)
{
    __shared__ float2 sv_pl[(NBINS + 1) * TPB];  // {sum, sumsq}, +dummy row, 34.8 KB
    __shared__ float  cred[NBINS][TPB / 64];
    __shared__ float  sqpart[TPB / 64];

    const int tid = threadIdx.x;

    #pragma unroll
    for (int k = 0; k < NBINS; ++k)
        sv_pl[k * TPB + tid] = make_float2(0.0f, 0.0f);
    // columns are thread-private until the epilogue fold; no barrier needed

    const float inv_a = 1.0f / alpha_p[0];
    const int   qoff  = 1 << (nbit_p[0] - 1);   // -Qn = 8 for nbit=4

    const long long n4     = n >> 2;
    const long long stride = (long long)BLOCKS * TPB;
    const float4* w4 = (const float4*)w;
    const float4* q4 = (const float4*)wq;

    float sq = 0.0f;
    unsigned long long clo = 0ull, chi = 0ull;   // 16 x 8-bit packed bin counters
    float cf[NBINS];
    #pragma unroll
    for (int k = 0; k < NBINS; ++k) cf[k] = 0.0f;
    int pend = 0;

    long long i = (long long)blockIdx.x * TPB + tid;
    if (i < n4) {
        float4 a = w4[i];
        float4 b = q4[i];
        for (;;) {
            const long long in  = i + stride;
            const bool     more = in < n4;
            float4 an, bn;
            if (more) { an = w4[in]; bn = q4[in]; }   // prefetch next iter

            float d0 = b.x - a.x, d1 = b.y - a.y, d2 = b.z - a.z, d3 = b.w - a.w;
            sq += d0 * d0 + d1 * d1 + d2 * d2 + d3 * d3;

            const int b0 = (((int)rintf(b.x * inv_a)) + qoff) & (NBINS - 1);
            const int b1 = (((int)rintf(b.y * inv_a)) + qoff) & (NBINS - 1);
            const int b2 = (((int)rintf(b.z * inv_a)) + qoff) & (NBINS - 1);
            const int b3 = (((int)rintf(b.w * inv_a)) + qoff) & (NBINS - 1);

            // packed register counts (exact)
            {
                unsigned long long t;
                t = 1ull << ((b0 & 7) << 3); clo += (b0 < 8) ? t : 0ull; chi += (b0 < 8) ? 0ull : t;
                t = 1ull << ((b1 & 7) << 3); clo += (b1 < 8) ? t : 0ull; chi += (b1 < 8) ? 0ull : t;
                t = 1ull << ((b2 & 7) << 3); clo += (b2 < 8) ? t : 0ull; chi += (b2 < 8) ? 0ull : t;
                t = 1ull << ((b3 & 7) << 3); clo += (b3 < 8) ? t : 0ull; chi += (b3 < 8) ? 0ull : t;
            }

            // dedup: merge duplicate bins into the first (live) slot.
            // A slot can only merge into a live representative (the && !e chains
            // guarantee it), so contributions never land in a dead slot.
            const bool e10 = (b1 == b0);
            const bool e20 = (b2 == b0);
            const bool e21 = (b2 == b1) && !e20;
            const bool e30 = (b3 == b0);
            const bool e31 = (b3 == b1) && !e30;
            const bool e32 = (b3 == b2) && !e30 && !e31;

            float sx0 = a.x, sx1 = a.y, sx2 = a.z, sx3 = a.w;
            float qx0 = a.x * a.x, qx1 = a.y * a.y, qx2 = a.z * a.z, qx3 = a.w * a.w;

            sx0 += e10 ? sx1 : 0.0f;  qx0 += e10 ? qx1 : 0.0f;
            sx0 += e20 ? sx2 : 0.0f;  qx0 += e20 ? qx2 : 0.0f;
            sx1 += e21 ? sx2 : 0.0f;  qx1 += e21 ? qx2 : 0.0f;
            sx0 += e30 ? sx3 : 0.0f;  qx0 += e30 ? qx3 : 0.0f;
            sx1 += e31 ? sx3 : 0.0f;  qx1 += e31 ? qx3 : 0.0f;
            sx2 += e32 ? sx3 : 0.0f;  qx2 += e32 ? qx3 : 0.0f;

            const int r1 = e10               ? DUMMY : b1;
            const int r2 = (e20 | e21)       ? DUMMY : b2;
            const int r3 = (e30 | e31 | e32) ? DUMMY : b3;
            const int a0 = (b0 << 8) + tid;
            const int a1 = (r1 << 8) + tid;
            const int a2 = (r2 << 8) + tid;
            const int a3 = (r3 << 8) + tid;

            // batched reads (distinct live addresses) -> ONE lgkmcnt wait
            float2 t0 = sv_pl[a0];
            float2 t1 = sv_pl[a1];
            float2 t2 = sv_pl[a2];
            float2 t3 = sv_pl[a3];
            t0.x += sx0; t0.y += qx0;
            t1.x += sx1; t1.y += qx1;
            t2.x += sx2; t2.y += qx2;
            t3.x += sx3; t3.y += qx3;
            sv_pl[a0] = t0;
            sv_pl[a1] = t1;
            sv_pl[a2] = t2;
            sv_pl[a3] = t3;

            // flush packed counters before any 8-bit field can overflow
            // (4 increments/iter max per field; flush every 32 iters -> <=128)
            if (++pend >= 32) {
                #pragma unroll
                for (int k = 0; k < 8; ++k) {
                    cf[k]     += (float)((clo >> (k * 8)) & 0xffull);
                    cf[k + 8] += (float)((chi >> (k * 8)) & 0xffull);
                }
                clo = 0ull; chi = 0ull; pend = 0;
            }

            if (!more) break;
            a = an; b = bn; i = in;
        }
    }

    // scalar tail (n divisible by 4 in practice; safety only)
    for (long long t = (n4 << 2) + (long long)blockIdx.x * TPB + tid; t < n; t += stride) {
        float av = w[t], bv = wq[t];
        float d = bv - av;
        sq += d * d;
        int bb = (((int)rintf(bv * inv_a)) + qoff) & (NBINS - 1);
        unsigned long long one = 1ull << ((bb & 7) << 3);
        clo += (bb < 8) ? one : 0ull; chi += (bb < 8) ? 0ull : one;
        int aa = (bb << 8) + tid;
        float2 tt = sv_pl[aa]; tt.x += av; tt.y += av * av; sv_pl[aa] = tt;
    }

    // final counter flush (pend <= 32 here, fields <= 129 < 255: safe)
    #pragma unroll
    for (int k = 0; k < 8; ++k) {
        cf[k]     += (float)((clo >> (k * 8)) & 0xffull);
        cf[k + 8] += (float)((chi >> (k * 8)) & 0xffull);
    }

    // wave-reduce sq
    for (int off = 32; off; off >>= 1) sq += __shfl_down(sq, off, 64);
    const int wave = tid >> 6, lane = tid & 63;
    if (lane == 0) sqpart[wave] = sq;

    // wave-reduce register counts into cred
    #pragma unroll
    for (int k = 0; k < NBINS; ++k) {
        float v = cf[k];
        for (int off = 32; off; off >>= 1) v += __shfl_down(v, off, 64);
        if (lane == 0) cred[k][wave] = v;
    }
    __syncthreads();

    if (tid < NBINS)
        partial[tid * BLOCKS + blockIdx.x] =
            cred[tid][0] + cred[tid][1] + cred[tid][2] + cred[tid][3];

    // fold 256 sv columns -> 32 block partials; wave v handles cells 16+v, 20+v, ...
    for (int c = 16 + wave; c < 48; c += 4) {
        const int bin = c & 15;
        float v = 0.0f;
        if (c < 32) {
            #pragma unroll
            for (int r = 0; r < TPB / 64; ++r)
                v += sv_pl[(bin << 8) + r * 64 + lane].x;
        } else {
            #pragma unroll
            for (int r = 0; r < TPB / 64; ++r)
                v += sv_pl[(bin << 8) + r * 64 + lane].y;
        }
        for (int off = 32; off; off >>= 1) v += __shfl_down(v, off, 64);
        if (lane == 0) partial[c * BLOCKS + blockIdx.x] = v;
    }
    if (tid == 0)
        partial[48 * BLOCKS + blockIdx.x] =
            sqpart[0] + sqpart[1] + sqpart[2] + sqpart[3];
}

__global__ __launch_bounds__(TPB) void binreg_final(
    const float* __restrict__ partial, float* __restrict__ out, long long n)
{
    __shared__ float cell[49];
    const int tid = threadIdx.x, wave = tid >> 6, lane = tid & 63;

    for (int c = wave; c < 49; c += 4) {
        float v0 = 0.0f, v1 = 0.0f, v2 = 0.0f, v3 = 0.0f;
        for (int r = lane; r < BLOCKS; r += 256) {
            v0 += partial[c * BLOCKS + r];
            v1 += partial[c * BLOCKS + r + 64];
            v2 += partial[c * BLOCKS + r + 128];
            v3 += partial[c * BLOCKS + r + 192];
        }
        float v = (v0 + v1) + (v2 + v3);
        for (int off = 32; off; off >>= 1) v += __shfl_down(v, off, 64);
        if (lane == 0) cell[c] = v;
    }
    __syncthreads();

    if (tid == 0) {
        float loss = cell[48] / (float)n;   // mean squared diff
        #pragma unroll
        for (int b = 0; b < NBINS; ++b) {
            float cnt = cell[b];
            float s   = cell[16 + b];
            float ss  = cell[32 + b];
            if (cnt > 1.0f)
                loss += (ss - s * s / cnt) / (cnt - 1.0f);  // unbiased var
        }
        out[0] = 0.1f * loss;   // LMBDA
    }
}

extern "C" void kernel_launch(void* const* d_in, const int* in_sizes, int n_in,
                              void* d_out, int out_size, void* d_ws, size_t ws_size,
                              hipStream_t stream)
{
    const float* w     = (const float*)d_in[0];
    const float* wq    = (const float*)d_in[1];
    const int*   nbit  = (const int*)d_in[2];
    const float* alpha = (const float*)d_in[3];
    float* out     = (float*)d_out;
    float* partial = (float*)d_ws;   // 49*BLOCKS floats, fully overwritten; no memset
    long long n = (long long)in_sizes[0];

    binreg_main<<<BLOCKS, TPB, 0, stream>>>(w, wq, alpha, nbit, partial, n);
    binreg_final<<<1, TPB, 0, stream>>>(partial, out, n);
}